// Round 12
// baseline (189.400 us; speedup 1.0000x reference)
//
#include <hip/hip_runtime.h>
#include <hip/hip_bf16.h>

#define BN_EPS 1e-5f
#define CB_SHIFT 9            // 512 nodes per coarse bucket
#define CB_NODES 512
#define CAP 32768             // padded per-bucket capacity (E/ncb ~ 8k; 4x headroom)
#define P1_CHUNK 4096
#define AGB 2048              // agg blocks (grid-stride)

typedef __attribute__((ext_vector_type(8))) short short8;
typedef __attribute__((ext_vector_type(4))) float f32x4;

__device__ __forceinline__ ushort f2bf(float x) {
    union { __hip_bfloat16 h; ushort u; } c;
    c.h = __float2bfloat16(x);          // RNE; compiler can emit v_cvt_pk
    return c.u;
}
__device__ __forceinline__ uint pk2(float a, float b) {
    union { __hip_bfloat162 h; uint u; } c;
    c.h = __float22bfloat162_rn(make_float2(a, b));
    return c.u;
}
__device__ __forceinline__ float bf2f(uint h) { return __uint_as_float(h << 16); }

__device__ __forceinline__ void unpack8(uint4 u, float* v) {
    v[0] = bf2f(u.x & 0xffffu); v[1] = bf2f(u.x >> 16);
    v[2] = bf2f(u.y & 0xffffu); v[3] = bf2f(u.y >> 16);
    v[4] = bf2f(u.z & 0xffffu); v[5] = bf2f(u.z >> 16);
    v[6] = bf2f(u.w & 0xffffu); v[7] = bf2f(u.w >> 16);
}
__device__ __forceinline__ uint4 pack8(const float* v) {
    uint4 w;
    w.x = pk2(v[0], v[1]);
    w.y = pk2(v[2], v[3]);
    w.z = pk2(v[4], v[5]);
    w.w = pk2(v[6], v[7]);
    return w;
}

// ---------------- weight pre-transpose: WT[out][K] bf16 (also zero-inits claim) ----------------

__global__ __launch_bounds__(256) void k_prepw(const float* __restrict__ W1,
                                               const float* __restrict__ W2,
                                               const float* __restrict__ W3,
                                               ushort* __restrict__ WT1,
                                               ushort* __restrict__ WT2,
                                               ushort* __restrict__ WT3,
                                               int* __restrict__ claim, int ncb) {
    int b = blockIdx.x;
    if (b == 0 && threadIdx.x < ncb) claim[threadIdx.x] = 0;
    const float* src; ushort* dst; int K, OUT, out;
    if (b < 64)       { out = b;       K = 256; OUT = 64;  src = W1; dst = WT1; }
    else if (b < 128) { out = b - 64;  K = 64;  OUT = 64;  src = W2; dst = WT2; }
    else              { out = b - 128; K = 64;  OUT = 256; src = W3; dst = WT3; }
    for (int k = threadIdx.x; k < K; k += 256)
        dst[(size_t)out * K + k] = f2bf(src[(size_t)k * OUT + out]);
}

// ---------------- CSR build: fixed-capacity buckets ----------------
// pass 1: scatter edges into bucket-padded key array. key = (dst_local<<17)|src (N<=131072)

__global__ __launch_bounds__(256) void k_p1(const int* __restrict__ src,
                                            const int* __restrict__ dst,
                                            int* __restrict__ claim,
                                            uint* __restrict__ keys, int E) {
    __shared__ int hist[128];
    __shared__ int wpos[128];
    int tid = threadIdx.x;
    int c0 = blockIdx.x * P1_CHUNK;
    if (tid < 128) hist[tid] = 0;
    __syncthreads();
    for (int i = tid; i < P1_CHUNK; i += 256) {
        int e = c0 + i;
        if (e < E) atomicAdd(&hist[dst[e] >> CB_SHIFT], 1);
    }
    __syncthreads();
    if (tid < 128) wpos[tid] = hist[tid] ? atomicAdd(&claim[tid], hist[tid]) : 0;
    __syncthreads();
    for (int i = tid; i < P1_CHUNK; i += 256) {
        int e = c0 + i;
        if (e < E) {
            int d = dst[e];
            int b = d >> CB_SHIFT;
            uint key = ((uint)(d & (CB_NODES - 1)) << 17) | (uint)src[e];
            int slot = atomicAdd(&wpos[b], 1);
            keys[(size_t)b * CAP + slot] = key;
        }
    }
}

// pass 2 per bucket: LDS hist -> local scan -> row{beg,deg}/dinv -> scatter col (padded space)

__global__ __launch_bounds__(256) void k_build(const uint* __restrict__ keys,
                                               const int* __restrict__ claim,
                                               int2* __restrict__ row,
                                               float* __restrict__ dinv,
                                               int* __restrict__ col, int n) {
    __shared__ int hist[CB_NODES];
    __shared__ int excl[CB_NODES];
    __shared__ int lpos[CB_NODES];
    __shared__ int ps[256];
    int t = threadIdx.x;
    int cb = blockIdx.x;
    int cnt = claim[cb];
    const uint* kb = keys + (size_t)cb * CAP;
    int base = cb * CAP;
    for (int i = t; i < CB_NODES; i += 256) { hist[i] = 0; lpos[i] = 0; }
    __syncthreads();
    for (int j = t; j < cnt; j += 256) atomicAdd(&hist[kb[j] >> 17], 1);
    __syncthreads();
    ps[t] = hist[2 * t] + hist[2 * t + 1];
    __syncthreads();
    for (int off = 1; off < 256; off <<= 1) {
        int v = ps[t];
        int a = (t >= off) ? ps[t - off] : 0;
        __syncthreads();
        ps[t] = v + a;
        __syncthreads();
    }
    int b0 = (t == 0) ? 0 : ps[t - 1];
    excl[2 * t] = b0;
    excl[2 * t + 1] = b0 + hist[2 * t];
    __syncthreads();
    for (int i = t; i < CB_NODES; i += 256) {
        int node = (cb << CB_SHIFT) + i;
        if (node < n) {
            row[node] = make_int2(base + excl[i], hist[i]);
            dinv[node] = rsqrtf((float)hist[i] + 1.0f);
        }
    }
    __syncthreads();
    for (int j = t; j < cnt; j += 256) {
        uint key = kb[j];
        int nl = key >> 17;
        col[base + excl[nl] + atomicAdd(&lpos[nl], 1)] = (int)(key & 0x1FFFFu);
    }
}

// ---------------- MFMA bf16 GEMM (double-buffered): C[n,OUT] = transform(A[n,K]) @ W ----------------

__global__ __launch_bounds__(256) void k_gemm_mfma(
    const float* __restrict__ Af, const ushort* __restrict__ Ab,
    const ushort* __restrict__ WT,
    ushort* __restrict__ Cb, float* __restrict__ Cf,
    const float* __restrict__ scale, const float* __restrict__ shift,
    const float* __restrict__ dinv,
    float* __restrict__ part, int nblk, int OUTW,
    int n, int K, int OUT)
{
    __shared__ ushort As[2][64][40];   // [buf][row][k]
    __shared__ ushort Wt[2][64][40];   // [buf][col][k]
    __shared__ float ssum[64][17];
    __shared__ float ssq[64][17];
    const int row0 = blockIdx.x * 64;
    const int col0 = blockIdx.y * 64;
    const int tid = threadIdx.x;
    const int wv = tid >> 6;
    const int lane = tid & 63;
    const int fr = lane & 15;
    const int kb = lane >> 4;

    const int ar  = tid >> 2;         // A stage: row 0..63
    const int akc = (tid & 3) << 3;   // A stage: k offset 0,8,16,24
    const int wc  = tid >> 2;         // W stage: col 0..63
    const int wkc = (tid & 3) << 3;   // W stage: k offset
    const int NT = K >> 5;

    f32x4 acc[4];
    acc[0] = acc[1] = acc[2] = acc[3] = (f32x4){0.f, 0.f, 0.f, 0.f};

    uint4 apack, wpack;

#define PREFETCH(k0)                                                                \
    {                                                                               \
        int gr = row0 + ar;                                                         \
        if (Af) {                                                                   \
            float v[8];                                                             \
            if (gr < n) {                                                           \
                const float* ap = Af + (size_t)gr * K + (k0) + akc;                 \
                float4 x0 = *(const float4*)ap;                                     \
                float4 x1 = *(const float4*)(ap + 4);                               \
                v[0] = x0.x; v[1] = x0.y; v[2] = x0.z; v[3] = x0.w;                 \
                v[4] = x1.x; v[5] = x1.y; v[6] = x1.z; v[7] = x1.w;                 \
            } else {                                                                \
                _Pragma("unroll") for (int j = 0; j < 8; ++j) v[j] = 0.f;           \
            }                                                                       \
            apack = pack8(v);                                                       \
        } else if (scale) {                                                         \
            float v[8];                                                             \
            if (gr < n) {                                                           \
                uint4 u = *(const uint4*)(Ab + (size_t)gr * K + (k0) + akc);        \
                unpack8(u, v);                                                      \
                _Pragma("unroll")                                                   \
                for (int j = 0; j < 8; ++j)                                         \
                    v[j] = fmaxf(v[j] * scale[(k0) + akc + j]                       \
                                 + shift[(k0) + akc + j], 0.f);                     \
            } else {                                                                \
                _Pragma("unroll") for (int j = 0; j < 8; ++j) v[j] = 0.f;           \
            }                                                                       \
            apack = pack8(v);                                                       \
        } else {                                                                    \
            apack = make_uint4(0, 0, 0, 0);                                         \
            if (gr < n) apack = *(const uint4*)(Ab + (size_t)gr * K + (k0) + akc);  \
        }                                                                           \
        wpack = *(const uint4*)(WT + (size_t)(col0 + wc) * K + (k0) + wkc);         \
    }

#define STORE(b)                                  \
    {                                             \
        *(uint4*)&As[b][ar][akc] = apack;         \
        *(uint4*)&Wt[b][wc][wkc] = wpack;         \
    }

    PREFETCH(0)
    STORE(0)
    __syncthreads();

    for (int t = 0; t < NT; ++t) {
        int buf = t & 1;
        if (t + 1 < NT) PREFETCH((t + 1) << 5)
        short8 a = *(const short8*)&As[buf][16 * wv + fr][kb << 3];
        #pragma unroll
        for (int ct = 0; ct < 4; ++ct) {
            short8 b = *(const short8*)&Wt[buf][ct * 16 + fr][kb << 3];
            acc[ct] = __builtin_amdgcn_mfma_f32_16x16x32_bf16(a, b, acc[ct], 0, 0, 0);
        }
        if (t + 1 < NT) {
            STORE(buf ^ 1)
            __syncthreads();
        }
    }
#undef PREFETCH
#undef STORE

    // epilogue: D row = 16*wv + kb*4 + r, col = ct*16 + fr
    const int contrib = wv * 4 + kb;   // 0..15
    #pragma unroll
    for (int ct = 0; ct < 4; ++ct) {
        float psum = 0.f, psq = 0.f;
        #pragma unroll
        for (int r = 0; r < 4; ++r) {
            int gr = row0 + 16 * wv + (kb << 2) + r;
            if (gr >= n) continue;
            float dv = dinv ? dinv[gr] : 1.0f;
            float val = acc[ct][r] * dv;
            int gc = col0 + ct * 16 + fr;
            if (Cb) Cb[(size_t)gr * OUT + gc] = f2bf(val);
            else    Cf[(size_t)gr * OUT + gc] = val;
            psum += val;
            psq += val * val;
        }
        if (part) {
            ssum[ct * 16 + fr][contrib] = psum;
            ssq[ct * 16 + fr][contrib] = psq;
        }
    }
    if (part) {
        __syncthreads();
        if (tid < 64) {
            float s = 0.f, s2 = 0.f;
            #pragma unroll
            for (int i = 0; i < 16; ++i) { s += ssum[tid][i]; s2 += ssq[tid][i]; }
            part[(size_t)blockIdx.x * OUTW + col0 + tid] = s;
            part[(size_t)(nblk + blockIdx.x) * OUTW + col0 + tid] = s2;
        }
    }
}

// ---------------- aggregation + fused BN partial stats (conv1/conv2) ----------------
// out[i] = dinv[i] * (Hs[i] + sum_{src} Hs[src]); grid-stride, 32 nodes/block-iter.
// 8-deep gather MLP.

__global__ __launch_bounds__(256) void k_agg_st(
    const ushort* __restrict__ Hs, const float* __restrict__ dinv,
    const int2* __restrict__ row, const int* __restrict__ col,
    ushort* __restrict__ outp, float* __restrict__ part, int n, int nblk)
{
    int tid = threadIdx.x;
    int sub = (tid & 63) >> 3;
    int wvb = tid >> 6;                 // wave in block 0..3
    int cg = (tid & 7) << 3;
    int nch = (n + 31) >> 5;
    float asum[8] = {0.f}, asq[8] = {0.f};
    for (int ch = blockIdx.x; ch < nch; ch += gridDim.x) {
        int node = (ch << 5) + (wvb << 3) + sub;
        if (node >= n) continue;
        float s[8], v[8];
        uint4 u = *(const uint4*)(Hs + (size_t)node * 64 + cg);
        unpack8(u, s);
        int2 rd = row[node];
        int b = rd.x, deg = rd.y;
        int j = 0;
        for (; j + 8 <= deg; j += 8) {
            int i0 = col[b + j],     i1 = col[b + j + 1], i2 = col[b + j + 2], i3 = col[b + j + 3];
            int i4 = col[b + j + 4], i5 = col[b + j + 5], i6 = col[b + j + 6], i7 = col[b + j + 7];
            uint4 u0 = *(const uint4*)(Hs + (size_t)i0 * 64 + cg);
            uint4 u1 = *(const uint4*)(Hs + (size_t)i1 * 64 + cg);
            uint4 u2 = *(const uint4*)(Hs + (size_t)i2 * 64 + cg);
            uint4 u3 = *(const uint4*)(Hs + (size_t)i3 * 64 + cg);
            uint4 u4 = *(const uint4*)(Hs + (size_t)i4 * 64 + cg);
            uint4 u5 = *(const uint4*)(Hs + (size_t)i5 * 64 + cg);
            uint4 u6 = *(const uint4*)(Hs + (size_t)i6 * 64 + cg);
            uint4 u7 = *(const uint4*)(Hs + (size_t)i7 * 64 + cg);
            unpack8(u0, v);
            #pragma unroll
            for (int q = 0; q < 8; ++q) s[q] += v[q];
            unpack8(u1, v);
            #pragma unroll
            for (int q = 0; q < 8; ++q) s[q] += v[q];
            unpack8(u2, v);
            #pragma unroll
            for (int q = 0; q < 8; ++q) s[q] += v[q];
            unpack8(u3, v);
            #pragma unroll
            for (int q = 0; q < 8; ++q) s[q] += v[q];
            unpack8(u4, v);
            #pragma unroll
            for (int q = 0; q < 8; ++q) s[q] += v[q];
            unpack8(u5, v);
            #pragma unroll
            for (int q = 0; q < 8; ++q) s[q] += v[q];
            unpack8(u6, v);
            #pragma unroll
            for (int q = 0; q < 8; ++q) s[q] += v[q];
            unpack8(u7, v);
            #pragma unroll
            for (int q = 0; q < 8; ++q) s[q] += v[q];
        }
        for (; j + 4 <= deg; j += 4) {
            int i0 = col[b + j], i1 = col[b + j + 1], i2 = col[b + j + 2], i3 = col[b + j + 3];
            uint4 u0 = *(const uint4*)(Hs + (size_t)i0 * 64 + cg);
            uint4 u1 = *(const uint4*)(Hs + (size_t)i1 * 64 + cg);
            uint4 u2 = *(const uint4*)(Hs + (size_t)i2 * 64 + cg);
            uint4 u3 = *(const uint4*)(Hs + (size_t)i3 * 64 + cg);
            unpack8(u0, v);
            #pragma unroll
            for (int q = 0; q < 8; ++q) s[q] += v[q];
            unpack8(u1, v);
            #pragma unroll
            for (int q = 0; q < 8; ++q) s[q] += v[q];
            unpack8(u2, v);
            #pragma unroll
            for (int q = 0; q < 8; ++q) s[q] += v[q];
            unpack8(u3, v);
            #pragma unroll
            for (int q = 0; q < 8; ++q) s[q] += v[q];
        }
        for (; j < deg; ++j) {
            uint4 u0 = *(const uint4*)(Hs + (size_t)col[b + j] * 64 + cg);
            unpack8(u0, v);
            #pragma unroll
            for (int q = 0; q < 8; ++q) s[q] += v[q];
        }
        float dn = dinv[node];
        float o[8];
        #pragma unroll
        for (int q = 0; q < 8; ++q) {
            o[q] = s[q] * dn;
            asum[q] += o[q];
            asq[q] += o[q] * o[q];
        }
        *(uint4*)(outp + (size_t)node * 64 + cg) = pack8(o);
    }
    __shared__ float ls[256][8];
    __shared__ float ls2[256][8];
    #pragma unroll
    for (int q = 0; q < 8; ++q) { ls[tid][q] = asum[q]; ls2[tid][q] = asq[q]; }
    __syncthreads();
    for (int off = 128; off >= 8; off >>= 1) {
        if (tid < off) {
            #pragma unroll
            for (int q = 0; q < 8; ++q) {
                ls[tid][q] += ls[tid + off][q];
                ls2[tid][q] += ls2[tid + off][q];
            }
        }
        __syncthreads();
    }
    if (tid < 8) {
        #pragma unroll
        for (int q = 0; q < 8; ++q) {
            part[(size_t)blockIdx.x * 64 + tid * 8 + q] = ls[tid][q];
            part[(size_t)(nblk + blockIdx.x) * 64 + tid * 8 + q] = ls2[tid][q];
        }
    }
}

// ---------------- aggregation with fused BN2+ReLU+dinv transform (conv3) ----------------

__global__ __launch_bounds__(256) void k_agg_tr(
    const ushort* __restrict__ Hs, const float* __restrict__ dinv,
    const int2* __restrict__ row, const int* __restrict__ col,
    ushort* __restrict__ outp, int n,
    const float* __restrict__ scale, const float* __restrict__ shift)
{
    int tid = threadIdx.x;
    int sub = (tid & 63) >> 3;
    int wvb = tid >> 6;
    int cg = (tid & 7) << 3;
    float sc[8], sh[8];
    #pragma unroll
    for (int q = 0; q < 8; ++q) { sc[q] = scale[cg + q]; sh[q] = shift[cg + q]; }
    int nch = (n + 31) >> 5;
    for (int ch = blockIdx.x; ch < nch; ch += gridDim.x) {
        int node = (ch << 5) + (wvb << 3) + sub;
        if (node >= n) continue;
        float s[8], v[8];
        {
            uint4 u = *(const uint4*)(Hs + (size_t)node * 64 + cg);
            unpack8(u, v);
            float dv = dinv[node];
            #pragma unroll
            for (int q = 0; q < 8; ++q) s[q] = fmaxf(v[q] * sc[q] + sh[q], 0.f) * dv;
        }
        int2 rd = row[node];
        int b = rd.x, deg = rd.y;
        int j = 0;
        for (; j + 8 <= deg; j += 8) {
            int i0 = col[b + j],     i1 = col[b + j + 1], i2 = col[b + j + 2], i3 = col[b + j + 3];
            int i4 = col[b + j + 4], i5 = col[b + j + 5], i6 = col[b + j + 6], i7 = col[b + j + 7];
            float d0 = dinv[i0], d1 = dinv[i1], d2 = dinv[i2], d3 = dinv[i3];
            float d4 = dinv[i4], d5 = dinv[i5], d6 = dinv[i6], d7 = dinv[i7];
            uint4 u0 = *(const uint4*)(Hs + (size_t)i0 * 64 + cg);
            uint4 u1 = *(const uint4*)(Hs + (size_t)i1 * 64 + cg);
            uint4 u2 = *(const uint4*)(Hs + (size_t)i2 * 64 + cg);
            uint4 u3 = *(const uint4*)(Hs + (size_t)i3 * 64 + cg);
            uint4 u4 = *(const uint4*)(Hs + (size_t)i4 * 64 + cg);
            uint4 u5 = *(const uint4*)(Hs + (size_t)i5 * 64 + cg);
            uint4 u6 = *(const uint4*)(Hs + (size_t)i6 * 64 + cg);
            uint4 u7 = *(const uint4*)(Hs + (size_t)i7 * 64 + cg);
            unpack8(u0, v);
            #pragma unroll
            for (int q = 0; q < 8; ++q) s[q] += fmaxf(v[q] * sc[q] + sh[q], 0.f) * d0;
            unpack8(u1, v);
            #pragma unroll
            for (int q = 0; q < 8; ++q) s[q] += fmaxf(v[q] * sc[q] + sh[q], 0.f) * d1;
            unpack8(u2, v);
            #pragma unroll
            for (int q = 0; q < 8; ++q) s[q] += fmaxf(v[q] * sc[q] + sh[q], 0.f) * d2;
            unpack8(u3, v);
            #pragma unroll
            for (int q = 0; q < 8; ++q) s[q] += fmaxf(v[q] * sc[q] + sh[q], 0.f) * d3;
            unpack8(u4, v);
            #pragma unroll
            for (int q = 0; q < 8; ++q) s[q] += fmaxf(v[q] * sc[q] + sh[q], 0.f) * d4;
            unpack8(u5, v);
            #pragma unroll
            for (int q = 0; q < 8; ++q) s[q] += fmaxf(v[q] * sc[q] + sh[q], 0.f) * d5;
            unpack8(u6, v);
            #pragma unroll
            for (int q = 0; q < 8; ++q) s[q] += fmaxf(v[q] * sc[q] + sh[q], 0.f) * d6;
            unpack8(u7, v);
            #pragma unroll
            for (int q = 0; q < 8; ++q) s[q] += fmaxf(v[q] * sc[q] + sh[q], 0.f) * d7;
        }
        for (; j < deg; ++j) {
            int i0 = col[b + j];
            float d0 = dinv[i0];
            uint4 u0 = *(const uint4*)(Hs + (size_t)i0 * 64 + cg);
            unpack8(u0, v);
            #pragma unroll
            for (int q = 0; q < 8; ++q) s[q] += fmaxf(v[q] * sc[q] + sh[q], 0.f) * d0;
        }
        float dn = dinv[node];
        float o[8];
        #pragma unroll
        for (int q = 0; q < 8; ++q) o[q] = s[q] * dn;
        *(uint4*)(outp + (size_t)node * 64 + cg) = pack8(o);
    }
}

// ---------------- BN stat finalize: one block per channel ----------------

__global__ __launch_bounds__(256) void k_bnstat2(const float* __restrict__ part,
                                                 const float* __restrict__ g,
                                                 const float* __restrict__ be,
                                                 float* __restrict__ scale,
                                                 float* __restrict__ shift,
                                                 int nblk, int W, float inv_n) {
    int c = blockIdx.x;          // channel
    int t = threadIdx.x;
    float s = 0.f, s2 = 0.f;
    for (int b = t; b < nblk; b += 256) {
        s  += part[(size_t)b * W + c];
        s2 += part[(size_t)(nblk + b) * W + c];
    }
    __shared__ float ls[256], ls2[256];
    ls[t] = s;
    ls2[t] = s2;
    __syncthreads();
    for (int off = 128; off > 0; off >>= 1) {
        if (t < off) {
            ls[t] += ls[t + off];
            ls2[t] += ls2[t + off];
        }
        __syncthreads();
    }
    if (t == 0) {
        float m = ls[0] * inv_n;
        float v = ls2[0] * inv_n - m * m;
        float sc = g[c] * rsqrtf(v + BN_EPS);
        scale[c] = sc;
        shift[c] = be[c] - m * sc;
    }
}

// ---------------- final: out = relu(h*scale[c] + shift[c] + x), h bf16, W=256 ----------------

__global__ void k_final_bf(const ushort* __restrict__ h, const float* __restrict__ x,
                           float* __restrict__ out,
                           const float* __restrict__ scale, const float* __restrict__ shift, int n) {
    int idx = blockIdx.x * blockDim.x + threadIdx.x;
    int total = n * 32;
    for (int i = idx; i < total; i += gridDim.x * blockDim.x) {
        int row = i >> 5;
        int c8 = (i & 31) << 3;
        uint4 u = *(const uint4*)(h + (size_t)row * 256 + c8);
        float v[8];
        unpack8(u, v);
        const float* xp = x + (size_t)row * 256 + c8;
        float4 x0 = *(const float4*)xp;
        float4 x1 = *(const float4*)(xp + 4);
        float xv[8] = {x0.x, x0.y, x0.z, x0.w, x1.x, x1.y, x1.z, x1.w};
        float o[8];
        #pragma unroll
        for (int j = 0; j < 8; ++j)
            o[j] = fmaxf(v[j] * scale[c8 + j] + shift[c8 + j] + xv[j], 0.f);
        float* op = out + (size_t)row * 256 + c8;
        *(float4*)op = make_float4(o[0], o[1], o[2], o[3]);
        *(float4*)(op + 4) = make_float4(o[4], o[5], o[6], o[7]);
    }
}

// ---------------- launch ----------------

extern "C" void kernel_launch(void* const* d_in, const int* in_sizes, int n_in,
                              void* d_out, int out_size, void* d_ws, size_t ws_size,
                              hipStream_t stream) {
    const float* x   = (const float*)d_in[0];
    const int*   ei  = (const int*)d_in[1];
    const int    N   = in_sizes[2];
    const int    E   = in_sizes[1] / 2;
    const float* W1  = (const float*)d_in[3];
    const float* g1  = (const float*)d_in[5];
    const float* be1 = (const float*)d_in[6];
    const float* W2  = (const float*)d_in[7];
    const float* g2  = (const float*)d_in[9];
    const float* be2 = (const float*)d_in[10];
    const float* W3  = (const float*)d_in[11];
    const float* g3  = (const float*)d_in[13];
    const float* be3 = (const float*)d_in[14];
    float* out = (float*)d_out;

    char* p = (char*)d_ws;
    auto alloc = [&](size_t bytes) {
        char* q = p;
        p += (bytes + 255) & ~(size_t)255;
        return q;
    };
    const int NCB = (N + CB_NODES - 1) >> CB_SHIFT;
    const int RT1 = (N + 63) / 64;       // gemm row tiles
    size_t part_elems = (size_t)2 * AGB * 64;
    size_t part_elems3 = (size_t)2 * RT1 * 256;
    if (part_elems3 > part_elems) part_elems = part_elems3;

    int*    claim  = (int*)alloc((size_t)NCB * 4);
    int2*   rowv   = (int2*)alloc((size_t)N * 8);
    float*  dinv   = (float*)alloc((size_t)N * 4);
    uint*   keys   = (uint*)alloc((size_t)NCB * CAP * 4);
    int*    colv   = (int*)alloc((size_t)NCB * CAP * 4);
    ushort* WT1    = (ushort*)alloc((size_t)64 * 256 * 2);
    ushort* WT2    = (ushort*)alloc((size_t)64 * 64 * 2);
    ushort* WT3    = (ushort*)alloc((size_t)256 * 64 * 2);
    ushort* bufAb  = (ushort*)alloc((size_t)N * 64 * 2);
    ushort* bufBb  = (ushort*)alloc((size_t)N * 64 * 2);
    ushort* bufCb  = (ushort*)alloc((size_t)N * 256 * 2);
    float*  part   = (float*)alloc(part_elems * 4);
    float*  scale  = (float*)alloc(256 * 4);
    float*  shift  = (float*)alloc(256 * 4);

    const int* srcp = ei;
    const int* dstp = ei + E;

    k_prepw<<<384, 256, 0, stream>>>(W1, W2, W3, WT1, WT2, WT3, claim, NCB);
    int p1b = (E + P1_CHUNK - 1) / P1_CHUNK;
    k_p1<<<p1b, 256, 0, stream>>>(srcp, dstp, claim, keys, E);
    k_build<<<NCB, 256, 0, stream>>>(keys, claim, rowv, dinv, colv, N);

    dim3 gemm_g(RT1, 1);
    dim3 gemm3_g(RT1, 4);

    // conv1: A1 = (x @ W1) * dinv (bf16) -> agg+stats -> G1 (pre-BN)
    k_gemm_mfma<<<gemm_g, 256, 0, stream>>>(x, nullptr, WT1, bufAb, nullptr,
                                            nullptr, nullptr, dinv,
                                            nullptr, 0, 0, N, 256, 64);
    k_agg_st<<<AGB, 256, 0, stream>>>(bufAb, dinv, rowv, colv, bufBb, part, N, AGB);
    k_bnstat2<<<64, 256, 0, stream>>>(part, g1, be1, scale, shift, AGB, 64, 1.0f / N);

    // conv2: BN1+ReLU fused into GEMM A-stage; ×dinv epilogue -> agg+stats -> G2 (pre-BN)
    k_gemm_mfma<<<gemm_g, 256, 0, stream>>>(nullptr, bufBb, WT2, bufAb, nullptr,
                                            scale, shift, dinv,
                                            nullptr, 0, 0, N, 64, 64);
    k_agg_st<<<AGB, 256, 0, stream>>>(bufAb, dinv, rowv, colv, bufBb, part, N, AGB);
    k_bnstat2<<<64, 256, 0, stream>>>(part, g2, be2, scale, shift, AGB, 64, 1.0f / N);

    // conv3 (agg-first): transform-agg -> GEMM3 (+fused BN3 partial stats) -> bufCb
    k_agg_tr<<<AGB, 256, 0, stream>>>(bufBb, dinv, rowv, colv, bufAb, N, scale, shift);
    k_gemm_mfma<<<gemm3_g, 256, 0, stream>>>(nullptr, bufAb, WT3, bufCb, nullptr,
                                             nullptr, nullptr, nullptr,
                                             part, RT1, 256, N, 64, 256);
    k_bnstat2<<<256, 256, 0, stream>>>(part, g3, be3, scale, shift, RT1, 256, 1.0f / N);

    k_final_bf<<<2048, 256, 0, stream>>>(bufCb, x, out, scale, shift, N);
}

// Round 13
// 172.655 us; speedup vs baseline: 1.0970x; 1.0970x over previous
//
#include <hip/hip_runtime.h>
#include <hip/hip_bf16.h>

#define BN_EPS 1e-5f
#define CB_SHIFT 9            // 512 nodes per coarse bucket
#define CB_NODES 512
#define CAP 32768             // padded per-bucket capacity
#define P1_CHUNK 2048
#define AGB 1024              // agg blocks (grid-stride)

typedef __attribute__((ext_vector_type(8))) short short8;
typedef __attribute__((ext_vector_type(4))) float f32x4;

__device__ __forceinline__ ushort f2bf(float x) {
    uint u = __float_as_uint(x);
    u += 0x7FFF + ((u >> 16) & 1);      // round-to-nearest-even
    return (ushort)(u >> 16);
}
__device__ __forceinline__ float bf2f(uint h) { return __uint_as_float(h << 16); }

__device__ __forceinline__ void unpack8(uint4 u, float* v) {
    v[0] = bf2f(u.x & 0xffffu); v[1] = bf2f(u.x >> 16);
    v[2] = bf2f(u.y & 0xffffu); v[3] = bf2f(u.y >> 16);
    v[4] = bf2f(u.z & 0xffffu); v[5] = bf2f(u.z >> 16);
    v[6] = bf2f(u.w & 0xffffu); v[7] = bf2f(u.w >> 16);
}
__device__ __forceinline__ uint4 pack8(const float* v) {
    uint4 w;
    w.x = (uint)f2bf(v[0]) | ((uint)f2bf(v[1]) << 16);
    w.y = (uint)f2bf(v[2]) | ((uint)f2bf(v[3]) << 16);
    w.z = (uint)f2bf(v[4]) | ((uint)f2bf(v[5]) << 16);
    w.w = (uint)f2bf(v[6]) | ((uint)f2bf(v[7]) << 16);
    return w;
}

// ---------------- weight pre-transpose: WT[out][K] bf16 (also zero-inits claim) ----------------

__global__ __launch_bounds__(256) void k_prepw(const float* __restrict__ W1,
                                               const float* __restrict__ W2,
                                               const float* __restrict__ W3,
                                               ushort* __restrict__ WT1,
                                               ushort* __restrict__ WT2,
                                               ushort* __restrict__ WT3,
                                               int* __restrict__ claim, int ncb) {
    int b = blockIdx.x;
    if (b == 0 && threadIdx.x < ncb) claim[threadIdx.x] = 0;
    const float* src; ushort* dst; int K, OUT, out;
    if (b < 64)       { out = b;       K = 256; OUT = 64;  src = W1; dst = WT1; }
    else if (b < 128) { out = b - 64;  K = 64;  OUT = 64;  src = W2; dst = WT2; }
    else              { out = b - 128; K = 64;  OUT = 256; src = W3; dst = WT3; }
    for (int k = threadIdx.x; k < K; k += 256)
        dst[(size_t)out * K + k] = f2bf(src[(size_t)k * OUT + out]);
}

// ---------------- fused: gemm1 (h1 = x @ W1, bf16, NO dinv) || p1 (CSR bucket scatter) ----------------
// blocks [0, ngemm): gemm rows; blocks [ngemm, ngemm+p1b): p1 chunks.
// key = (dst_local<<17)|src  (requires N <= 131072)

__global__ __launch_bounds__(256) void k_p1gemm1(
    const float* __restrict__ Af, const ushort* __restrict__ WT,
    ushort* __restrict__ Cb, int n, int K, int OUT, int ngemm,
    const int* __restrict__ src, const int* __restrict__ dst,
    int* __restrict__ claim, uint* __restrict__ keys, int E)
{
    __shared__ ushort As[2][64][40];
    __shared__ ushort Wt[2][64][40];
    __shared__ int hist[128];
    __shared__ int wpos[128];
    const int tid = threadIdx.x;

    if (blockIdx.x >= ngemm) {
        // ---- p1 path ----
        int c0 = (blockIdx.x - ngemm) * P1_CHUNK;
        if (tid < 128) hist[tid] = 0;
        __syncthreads();
        for (int i = tid; i < P1_CHUNK; i += 256) {
            int e = c0 + i;
            if (e < E) atomicAdd(&hist[dst[e] >> CB_SHIFT], 1);
        }
        __syncthreads();
        if (tid < 128) wpos[tid] = hist[tid] ? atomicAdd(&claim[tid], hist[tid]) : 0;
        __syncthreads();
        for (int i = tid; i < P1_CHUNK; i += 256) {
            int e = c0 + i;
            if (e < E) {
                int d = dst[e];
                int b = d >> CB_SHIFT;
                uint key = ((uint)(d & (CB_NODES - 1)) << 17) | (uint)src[e];
                int slot = atomicAdd(&wpos[b], 1);
                keys[(size_t)b * CAP + slot] = key;
            }
        }
        return;
    }

    // ---- gemm path (f32 A, bf16 out, no dinv, no stats) ----
    const int row0 = blockIdx.x * 64;
    const int wv = tid >> 6;
    const int lane = tid & 63;
    const int fr = lane & 15;
    const int kb = lane >> 4;
    const int ar  = tid >> 2;
    const int akc = (tid & 3) << 3;
    const int wc  = tid >> 2;
    const int wkc = (tid & 3) << 3;
    const int NT = K >> 5;

    f32x4 acc[4];
    acc[0] = acc[1] = acc[2] = acc[3] = (f32x4){0.f, 0.f, 0.f, 0.f};
    uint4 apack, wpack;

#define PREFETCH(k0)                                                    \
    {                                                                   \
        int gr = row0 + ar;                                             \
        float v[8];                                                     \
        if (gr < n) {                                                   \
            const float* ap = Af + (size_t)gr * K + (k0) + akc;         \
            float4 x0 = *(const float4*)ap;                             \
            float4 x1 = *(const float4*)(ap + 4);                       \
            v[0] = x0.x; v[1] = x0.y; v[2] = x0.z; v[3] = x0.w;         \
            v[4] = x1.x; v[5] = x1.y; v[6] = x1.z; v[7] = x1.w;         \
        } else {                                                        \
            _Pragma("unroll") for (int j = 0; j < 8; ++j) v[j] = 0.f;   \
        }                                                               \
        apack = pack8(v);                                               \
        wpack = *(const uint4*)(WT + (size_t)wc * K + (k0) + wkc);      \
    }
#define STORE(b)                                  \
    {                                             \
        *(uint4*)&As[b][ar][akc] = apack;         \
        *(uint4*)&Wt[b][wc][wkc] = wpack;         \
    }

    PREFETCH(0)
    STORE(0)
    __syncthreads();
    for (int t = 0; t < NT; ++t) {
        int buf = t & 1;
        if (t + 1 < NT) PREFETCH((t + 1) << 5)
        short8 a = *(const short8*)&As[buf][16 * wv + fr][kb << 3];
        #pragma unroll
        for (int ct = 0; ct < 4; ++ct) {
            short8 b = *(const short8*)&Wt[buf][ct * 16 + fr][kb << 3];
            acc[ct] = __builtin_amdgcn_mfma_f32_16x16x32_bf16(a, b, acc[ct], 0, 0, 0);
        }
        if (t + 1 < NT) {
            STORE(buf ^ 1)
            __syncthreads();
        }
    }
#undef PREFETCH
#undef STORE

    #pragma unroll
    for (int ct = 0; ct < 4; ++ct) {
        #pragma unroll
        for (int r = 0; r < 4; ++r) {
            int gr = row0 + 16 * wv + (kb << 2) + r;
            if (gr >= n) continue;
            Cb[(size_t)gr * OUT + ct * 16 + fr] = f2bf(acc[ct][r]);
        }
    }
}

// pass 2 per bucket: LDS hist -> local scan -> row{beg,deg}/dinv -> scatter col (padded space)

__global__ __launch_bounds__(256) void k_build(const uint* __restrict__ keys,
                                               const int* __restrict__ claim,
                                               int2* __restrict__ row,
                                               float* __restrict__ dinv,
                                               int* __restrict__ col, int n) {
    __shared__ int hist[CB_NODES];
    __shared__ int excl[CB_NODES];
    __shared__ int lpos[CB_NODES];
    __shared__ int ps[256];
    int t = threadIdx.x;
    int cb = blockIdx.x;
    int cnt = claim[cb];
    const uint* kb = keys + (size_t)cb * CAP;
    int base = cb * CAP;
    for (int i = t; i < CB_NODES; i += 256) { hist[i] = 0; lpos[i] = 0; }
    __syncthreads();
    for (int j = t; j < cnt; j += 256) atomicAdd(&hist[kb[j] >> 17], 1);
    __syncthreads();
    ps[t] = hist[2 * t] + hist[2 * t + 1];
    __syncthreads();
    for (int off = 1; off < 256; off <<= 1) {
        int v = ps[t];
        int a = (t >= off) ? ps[t - off] : 0;
        __syncthreads();
        ps[t] = v + a;
        __syncthreads();
    }
    int b0 = (t == 0) ? 0 : ps[t - 1];
    excl[2 * t] = b0;
    excl[2 * t + 1] = b0 + hist[2 * t];
    __syncthreads();
    for (int i = t; i < CB_NODES; i += 256) {
        int node = (cb << CB_SHIFT) + i;
        if (node < n) {
            row[node] = make_int2(base + excl[i], hist[i]);
            dinv[node] = rsqrtf((float)hist[i] + 1.0f);
        }
    }
    __syncthreads();
    for (int j = t; j < cnt; j += 256) {
        uint key = kb[j];
        int nl = key >> 17;
        col[base + excl[nl] + atomicAdd(&lpos[nl], 1)] = (int)(key & 0x1FFFFu);
    }
}

// ---------------- MFMA bf16 GEMM (double-buffered): C[n,OUT] = transform(A[n,K]) @ W ----------------

__global__ __launch_bounds__(256) void k_gemm_mfma(
    const float* __restrict__ Af, const ushort* __restrict__ Ab,
    const ushort* __restrict__ WT,
    ushort* __restrict__ Cb, float* __restrict__ Cf,
    const float* __restrict__ scale, const float* __restrict__ shift,
    const float* __restrict__ dinv,
    float* __restrict__ part, int nblk, int OUTW,
    int n, int K, int OUT)
{
    __shared__ ushort As[2][64][40];   // [buf][row][k]
    __shared__ ushort Wt[2][64][40];   // [buf][col][k]
    __shared__ float ssum[64][17];
    __shared__ float ssq[64][17];
    const int row0 = blockIdx.x * 64;
    const int col0 = blockIdx.y * 64;
    const int tid = threadIdx.x;
    const int wv = tid >> 6;
    const int lane = tid & 63;
    const int fr = lane & 15;
    const int kb = lane >> 4;

    const int ar  = tid >> 2;
    const int akc = (tid & 3) << 3;
    const int wc  = tid >> 2;
    const int wkc = (tid & 3) << 3;
    const int NT = K >> 5;

    f32x4 acc[4];
    acc[0] = acc[1] = acc[2] = acc[3] = (f32x4){0.f, 0.f, 0.f, 0.f};

    uint4 apack, wpack;

#define PREFETCH(k0)                                                                \
    {                                                                               \
        int gr = row0 + ar;                                                         \
        if (Af) {                                                                   \
            float v[8];                                                             \
            if (gr < n) {                                                           \
                const float* ap = Af + (size_t)gr * K + (k0) + akc;                 \
                float4 x0 = *(const float4*)ap;                                     \
                float4 x1 = *(const float4*)(ap + 4);                               \
                v[0] = x0.x; v[1] = x0.y; v[2] = x0.z; v[3] = x0.w;                 \
                v[4] = x1.x; v[5] = x1.y; v[6] = x1.z; v[7] = x1.w;                 \
            } else {                                                                \
                _Pragma("unroll") for (int j = 0; j < 8; ++j) v[j] = 0.f;           \
            }                                                                       \
            apack = pack8(v);                                                       \
        } else if (scale) {                                                         \
            float v[8];                                                             \
            if (gr < n) {                                                           \
                uint4 u = *(const uint4*)(Ab + (size_t)gr * K + (k0) + akc);        \
                unpack8(u, v);                                                      \
                _Pragma("unroll")                                                   \
                for (int j = 0; j < 8; ++j)                                         \
                    v[j] = fmaxf(v[j] * scale[(k0) + akc + j]                       \
                                 + shift[(k0) + akc + j], 0.f);                     \
            } else {                                                                \
                _Pragma("unroll") for (int j = 0; j < 8; ++j) v[j] = 0.f;           \
            }                                                                       \
            apack = pack8(v);                                                       \
        } else {                                                                    \
            apack = make_uint4(0, 0, 0, 0);                                         \
            if (gr < n) apack = *(const uint4*)(Ab + (size_t)gr * K + (k0) + akc);  \
        }                                                                           \
        wpack = *(const uint4*)(WT + (size_t)(col0 + wc) * K + (k0) + wkc);         \
    }

#define STORE(b)                                  \
    {                                             \
        *(uint4*)&As[b][ar][akc] = apack;         \
        *(uint4*)&Wt[b][wc][wkc] = wpack;         \
    }

    PREFETCH(0)
    STORE(0)
    __syncthreads();

    for (int t = 0; t < NT; ++t) {
        int buf = t & 1;
        if (t + 1 < NT) PREFETCH((t + 1) << 5)
        short8 a = *(const short8*)&As[buf][16 * wv + fr][kb << 3];
        #pragma unroll
        for (int ct = 0; ct < 4; ++ct) {
            short8 b = *(const short8*)&Wt[buf][ct * 16 + fr][kb << 3];
            acc[ct] = __builtin_amdgcn_mfma_f32_16x16x32_bf16(a, b, acc[ct], 0, 0, 0);
        }
        if (t + 1 < NT) {
            STORE(buf ^ 1)
            __syncthreads();
        }
    }
#undef PREFETCH
#undef STORE

    // epilogue: D row = 16*wv + kb*4 + r, col = ct*16 + fr
    const int contrib = wv * 4 + kb;   // 0..15
    #pragma unroll
    for (int ct = 0; ct < 4; ++ct) {
        float psum = 0.f, psq = 0.f;
        #pragma unroll
        for (int r = 0; r < 4; ++r) {
            int gr = row0 + 16 * wv + (kb << 2) + r;
            if (gr >= n) continue;
            float dv = dinv ? dinv[gr] : 1.0f;
            float val = acc[ct][r] * dv;
            int gc = col0 + ct * 16 + fr;
            if (Cb) Cb[(size_t)gr * OUT + gc] = f2bf(val);
            else    Cf[(size_t)gr * OUT + gc] = val;
            psum += val;
            psq += val * val;
        }
        if (part) {
            ssum[ct * 16 + fr][contrib] = psum;
            ssq[ct * 16 + fr][contrib] = psq;
        }
    }
    if (part) {
        __syncthreads();
        if (tid < 64) {
            float s = 0.f, s2 = 0.f;
            #pragma unroll
            for (int i = 0; i < 16; ++i) { s += ssum[tid][i]; s2 += ssq[tid][i]; }
            part[(size_t)blockIdx.x * OUTW + col0 + tid] = s;
            part[(size_t)(nblk + blockIdx.x) * OUTW + col0 + tid] = s2;
        }
    }
}

// ---------------- aggregation + fused BN partial stats (conv1/conv2) ----------------
// gdv == null:  out[i] = dinv[i] * (Hs[i] + sum_{src} Hs[src])        (Hs pre-scaled by dinv)
// gdv != null:  out[i] = dinv[i] * (h[i]*gdv[i] + sum_{src} h[src]*gdv[src])   (h unscaled)

__global__ __launch_bounds__(256) void k_agg_st(
    const ushort* __restrict__ Hs, const float* __restrict__ dinv,
    const int2* __restrict__ row, const int* __restrict__ col,
    ushort* __restrict__ outp, float* __restrict__ part, int n, int nblk,
    const float* __restrict__ gdv)
{
    int tid = threadIdx.x;
    int sub = (tid & 63) >> 3;
    int wvb = tid >> 6;                 // wave in block 0..3
    int cg = (tid & 7) << 3;
    int nch = (n + 31) >> 5;
    float asum[8] = {0.f}, asq[8] = {0.f};
    for (int ch = blockIdx.x; ch < nch; ch += gridDim.x) {
        int node = (ch << 5) + (wvb << 3) + sub;
        if (node >= n) continue;
        float s[8], v[8];
        uint4 u = *(const uint4*)(Hs + (size_t)node * 64 + cg);
        unpack8(u, s);
        if (gdv) {
            float dvn = gdv[node];
            #pragma unroll
            for (int q = 0; q < 8; ++q) s[q] *= dvn;
        }
        int2 rd = row[node];
        int b = rd.x, deg = rd.y;
        int j = 0;
        if (gdv) {
            for (; j + 4 <= deg; j += 4) {
                int i0 = col[b + j], i1 = col[b + j + 1], i2 = col[b + j + 2], i3 = col[b + j + 3];
                float d0 = gdv[i0], d1 = gdv[i1], d2 = gdv[i2], d3 = gdv[i3];
                uint4 u0 = *(const uint4*)(Hs + (size_t)i0 * 64 + cg);
                uint4 u1 = *(const uint4*)(Hs + (size_t)i1 * 64 + cg);
                uint4 u2 = *(const uint4*)(Hs + (size_t)i2 * 64 + cg);
                uint4 u3 = *(const uint4*)(Hs + (size_t)i3 * 64 + cg);
                unpack8(u0, v);
                #pragma unroll
                for (int q = 0; q < 8; ++q) s[q] += v[q] * d0;
                unpack8(u1, v);
                #pragma unroll
                for (int q = 0; q < 8; ++q) s[q] += v[q] * d1;
                unpack8(u2, v);
                #pragma unroll
                for (int q = 0; q < 8; ++q) s[q] += v[q] * d2;
                unpack8(u3, v);
                #pragma unroll
                for (int q = 0; q < 8; ++q) s[q] += v[q] * d3;
            }
            for (; j < deg; ++j) {
                int i0 = col[b + j];
                float d0 = gdv[i0];
                uint4 u0 = *(const uint4*)(Hs + (size_t)i0 * 64 + cg);
                unpack8(u0, v);
                #pragma unroll
                for (int q = 0; q < 8; ++q) s[q] += v[q] * d0;
            }
        } else {
            for (; j + 4 <= deg; j += 4) {
                int i0 = col[b + j], i1 = col[b + j + 1], i2 = col[b + j + 2], i3 = col[b + j + 3];
                uint4 u0 = *(const uint4*)(Hs + (size_t)i0 * 64 + cg);
                uint4 u1 = *(const uint4*)(Hs + (size_t)i1 * 64 + cg);
                uint4 u2 = *(const uint4*)(Hs + (size_t)i2 * 64 + cg);
                uint4 u3 = *(const uint4*)(Hs + (size_t)i3 * 64 + cg);
                unpack8(u0, v);
                #pragma unroll
                for (int q = 0; q < 8; ++q) s[q] += v[q];
                unpack8(u1, v);
                #pragma unroll
                for (int q = 0; q < 8; ++q) s[q] += v[q];
                unpack8(u2, v);
                #pragma unroll
                for (int q = 0; q < 8; ++q) s[q] += v[q];
                unpack8(u3, v);
                #pragma unroll
                for (int q = 0; q < 8; ++q) s[q] += v[q];
            }
            for (; j < deg; ++j) {
                uint4 u0 = *(const uint4*)(Hs + (size_t)col[b + j] * 64 + cg);
                unpack8(u0, v);
                #pragma unroll
                for (int q = 0; q < 8; ++q) s[q] += v[q];
            }
        }
        float dn = dinv[node];
        float o[8];
        #pragma unroll
        for (int q = 0; q < 8; ++q) {
            o[q] = s[q] * dn;
            asum[q] += o[q];
            asq[q] += o[q] * o[q];
        }
        *(uint4*)(outp + (size_t)node * 64 + cg) = pack8(o);
    }
    __shared__ float ls[256][8];
    __shared__ float ls2[256][8];
    #pragma unroll
    for (int q = 0; q < 8; ++q) { ls[tid][q] = asum[q]; ls2[tid][q] = asq[q]; }
    __syncthreads();
    for (int off = 128; off >= 8; off >>= 1) {
        if (tid < off) {
            #pragma unroll
            for (int q = 0; q < 8; ++q) {
                ls[tid][q] += ls[tid + off][q];
                ls2[tid][q] += ls2[tid + off][q];
            }
        }
        __syncthreads();
    }
    if (tid < 8) {
        #pragma unroll
        for (int q = 0; q < 8; ++q) {
            part[(size_t)blockIdx.x * 64 + tid * 8 + q] = ls[tid][q];
            part[(size_t)(nblk + blockIdx.x) * 64 + tid * 8 + q] = ls2[tid][q];
        }
    }
}

// ---------------- aggregation with fused BN2+ReLU+dinv transform (conv3) ----------------

__global__ __launch_bounds__(256) void k_agg_tr(
    const ushort* __restrict__ Hs, const float* __restrict__ dinv,
    const int2* __restrict__ row, const int* __restrict__ col,
    ushort* __restrict__ outp, int n,
    const float* __restrict__ scale, const float* __restrict__ shift)
{
    int tid = threadIdx.x;
    int sub = (tid & 63) >> 3;
    int wvb = tid >> 6;
    int cg = (tid & 7) << 3;
    float sc[8], sh[8];
    #pragma unroll
    for (int q = 0; q < 8; ++q) { sc[q] = scale[cg + q]; sh[q] = shift[cg + q]; }
    int nch = (n + 31) >> 5;
    for (int ch = blockIdx.x; ch < nch; ch += gridDim.x) {
        int node = (ch << 5) + (wvb << 3) + sub;
        if (node >= n) continue;
        float s[8], v[8];
        {
            uint4 u = *(const uint4*)(Hs + (size_t)node * 64 + cg);
            unpack8(u, v);
            float dv = dinv[node];
            #pragma unroll
            for (int q = 0; q < 8; ++q) s[q] = fmaxf(v[q] * sc[q] + sh[q], 0.f) * dv;
        }
        int2 rd = row[node];
        int b = rd.x, deg = rd.y;
        int j = 0;
        for (; j + 4 <= deg; j += 4) {
            int i0 = col[b + j], i1 = col[b + j + 1], i2 = col[b + j + 2], i3 = col[b + j + 3];
            float d0 = dinv[i0], d1 = dinv[i1], d2 = dinv[i2], d3 = dinv[i3];
            uint4 u0 = *(const uint4*)(Hs + (size_t)i0 * 64 + cg);
            uint4 u1 = *(const uint4*)(Hs + (size_t)i1 * 64 + cg);
            uint4 u2 = *(const uint4*)(Hs + (size_t)i2 * 64 + cg);
            uint4 u3 = *(const uint4*)(Hs + (size_t)i3 * 64 + cg);
            unpack8(u0, v);
            #pragma unroll
            for (int q = 0; q < 8; ++q) s[q] += fmaxf(v[q] * sc[q] + sh[q], 0.f) * d0;
            unpack8(u1, v);
            #pragma unroll
            for (int q = 0; q < 8; ++q) s[q] += fmaxf(v[q] * sc[q] + sh[q], 0.f) * d1;
            unpack8(u2, v);
            #pragma unroll
            for (int q = 0; q < 8; ++q) s[q] += fmaxf(v[q] * sc[q] + sh[q], 0.f) * d2;
            unpack8(u3, v);
            #pragma unroll
            for (int q = 0; q < 8; ++q) s[q] += fmaxf(v[q] * sc[q] + sh[q], 0.f) * d3;
        }
        for (; j < deg; ++j) {
            int i0 = col[b + j];
            float d0 = dinv[i0];
            uint4 u0 = *(const uint4*)(Hs + (size_t)i0 * 64 + cg);
            unpack8(u0, v);
            #pragma unroll
            for (int q = 0; q < 8; ++q) s[q] += fmaxf(v[q] * sc[q] + sh[q], 0.f) * d0;
        }
        float dn = dinv[node];
        float o[8];
        #pragma unroll
        for (int q = 0; q < 8; ++q) o[q] = s[q] * dn;
        *(uint4*)(outp + (size_t)node * 64 + cg) = pack8(o);
    }
}

// ---------------- BN stat finalize: one block per channel ----------------

__global__ __launch_bounds__(256) void k_bnstat2(const float* __restrict__ part,
                                                 const float* __restrict__ g,
                                                 const float* __restrict__ be,
                                                 float* __restrict__ scale,
                                                 float* __restrict__ shift,
                                                 int nblk, int W, float inv_n) {
    int c = blockIdx.x;          // channel
    int t = threadIdx.x;
    float s = 0.f, s2 = 0.f;
    for (int b = t; b < nblk; b += 256) {
        s  += part[(size_t)b * W + c];
        s2 += part[(size_t)(nblk + b) * W + c];
    }
    __shared__ float ls[256], ls2[256];
    ls[t] = s;
    ls2[t] = s2;
    __syncthreads();
    for (int off = 128; off > 0; off >>= 1) {
        if (t < off) {
            ls[t] += ls[t + off];
            ls2[t] += ls2[t + off];
        }
        __syncthreads();
    }
    if (t == 0) {
        float m = ls[0] * inv_n;
        float v = ls2[0] * inv_n - m * m;
        float sc = g[c] * rsqrtf(v + BN_EPS);
        scale[c] = sc;
        shift[c] = be[c] - m * sc;
    }
}

// ---------------- final: out = relu(h*scale[c] + shift[c] + x), h bf16, W=256 ----------------

__global__ void k_final_bf(const ushort* __restrict__ h, const float* __restrict__ x,
                           float* __restrict__ out,
                           const float* __restrict__ scale, const float* __restrict__ shift, int n) {
    int idx = blockIdx.x * blockDim.x + threadIdx.x;
    int total = n * 32;
    for (int i = idx; i < total; i += gridDim.x * blockDim.x) {
        int row = i >> 5;
        int c8 = (i & 31) << 3;
        uint4 u = *(const uint4*)(h + (size_t)row * 256 + c8);
        float v[8];
        unpack8(u, v);
        const float* xp = x + (size_t)row * 256 + c8;
        float4 x0 = *(const float4*)xp;
        float4 x1 = *(const float4*)(xp + 4);
        float xv[8] = {x0.x, x0.y, x0.z, x0.w, x1.x, x1.y, x1.z, x1.w};
        float o[8];
        #pragma unroll
        for (int j = 0; j < 8; ++j)
            o[j] = fmaxf(v[j] * scale[c8 + j] + shift[c8 + j] + xv[j], 0.f);
        float* op = out + (size_t)row * 256 + c8;
        *(float4*)op = make_float4(o[0], o[1], o[2], o[3]);
        *(float4*)(op + 4) = make_float4(o[4], o[5], o[6], o[7]);
    }
}

// ---------------- launch ----------------

extern "C" void kernel_launch(void* const* d_in, const int* in_sizes, int n_in,
                              void* d_out, int out_size, void* d_ws, size_t ws_size,
                              hipStream_t stream) {
    const float* x   = (const float*)d_in[0];
    const int*   ei  = (const int*)d_in[1];
    const int    N   = in_sizes[2];
    const int    E   = in_sizes[1] / 2;
    const float* W1  = (const float*)d_in[3];
    const float* g1  = (const float*)d_in[5];
    const float* be1 = (const float*)d_in[6];
    const float* W2  = (const float*)d_in[7];
    const float* g2  = (const float*)d_in[9];
    const float* be2 = (const float*)d_in[10];
    const float* W3  = (const float*)d_in[11];
    const float* g3  = (const float*)d_in[13];
    const float* be3 = (const float*)d_in[14];
    float* out = (float*)d_out;

    char* p = (char*)d_ws;
    auto alloc = [&](size_t bytes) {
        char* q = p;
        p += (bytes + 255) & ~(size_t)255;
        return q;
    };
    const int NCB = (N + CB_NODES - 1) >> CB_SHIFT;
    const int RT1 = (N + 63) / 64;       // gemm row tiles
    size_t part_elems = (size_t)2 * AGB * 64;
    size_t part_elems3 = (size_t)2 * RT1 * 256;
    if (part_elems3 > part_elems) part_elems = part_elems3;

    int*    claim  = (int*)alloc((size_t)NCB * 4);
    int2*   rowv   = (int2*)alloc((size_t)N * 8);
    float*  dinv   = (float*)alloc((size_t)N * 4);
    uint*   keys   = (uint*)alloc((size_t)NCB * CAP * 4);
    int*    colv   = (int*)alloc((size_t)NCB * CAP * 4);
    ushort* WT1    = (ushort*)alloc((size_t)64 * 256 * 2);
    ushort* WT2    = (ushort*)alloc((size_t)64 * 64 * 2);
    ushort* WT3    = (ushort*)alloc((size_t)256 * 64 * 2);
    ushort* bufAb  = (ushort*)alloc((size_t)N * 64 * 2);
    ushort* bufBb  = (ushort*)alloc((size_t)N * 64 * 2);
    ushort* bufCb  = (ushort*)alloc((size_t)N * 256 * 2);
    float*  part   = (float*)alloc(part_elems * 4);
    float*  scale  = (float*)alloc(256 * 4);
    float*  shift  = (float*)alloc(256 * 4);

    const int* srcp = ei;
    const int* dstp = ei + E;

    k_prepw<<<384, 256, 0, stream>>>(W1, W2, W3, WT1, WT2, WT3, claim, NCB);
    int p1b = (E + P1_CHUNK - 1) / P1_CHUNK;

    // fused: gemm1 (h1 = x@W1, unscaled bf16) || p1 (CSR scatter)
    k_p1gemm1<<<RT1 + p1b, 256, 0, stream>>>(x, WT1, bufAb, N, 256, 64, RT1,
                                             srcp, dstp, claim, keys, E);
    k_build<<<NCB, 256, 0, stream>>>(keys, claim, rowv, dinv, colv, N);

    dim3 gemm_g(RT1, 1);
    dim3 gemm3_g(RT1, 4);

    // conv1 agg: dinv applied at gather (h1 unscaled) + stats
    k_agg_st<<<AGB, 256, 0, stream>>>(bufAb, dinv, rowv, colv, bufBb, part, N, AGB, dinv);
    k_bnstat2<<<64, 256, 0, stream>>>(part, g1, be1, scale, shift, AGB, 64, 1.0f / N);

    // conv2: BN1+ReLU fused into GEMM A-stage; ×dinv epilogue -> agg+stats -> G2 (pre-BN)
    k_gemm_mfma<<<gemm_g, 256, 0, stream>>>(nullptr, bufBb, WT2, bufAb, nullptr,
                                            scale, shift, dinv,
                                            nullptr, 0, 0, N, 64, 64);
    k_agg_st<<<AGB, 256, 0, stream>>>(bufAb, dinv, rowv, colv, bufBb, part, N, AGB, nullptr);
    k_bnstat2<<<64, 256, 0, stream>>>(part, g2, be2, scale, shift, AGB, 64, 1.0f / N);

    // conv3 (agg-first): transform-agg -> GEMM3 (+fused BN3 partial stats) -> bufCb
    k_agg_tr<<<AGB, 256, 0, stream>>>(bufBb, dinv, rowv, colv, bufAb, N, scale, shift);
    k_gemm_mfma<<<gemm3_g, 256, 0, stream>>>(nullptr, bufAb, WT3, bufCb, nullptr,
                                             nullptr, nullptr, nullptr,
                                             part, RT1, 256, N, 64, 256);
    k_bnstat2<<<256, 256, 0, stream>>>(part, g3, be3, scale, shift, RT1, 256, 1.0f / N);

    k_final_bf<<<2048, 256, 0, stream>>>(bufCb, x, out, scale, shift, N);
}